// Round 1
// baseline (614.521 us; speedup 1.0000x reference)
//
#include <hip/hip_runtime.h>

#define BATCH 4096
#define T 64
#define D 64

struct GPtrs {
    const int* h0[5]; const int* h1[5];
    const int* r0[5]; const int* r1[5];
    const int* t0[5]; const int* t1[5];
};

__device__ __forceinline__ float sigmoidf_(float x) {
    return 1.0f / (1.0f + __expf(-x));
}
__device__ __forceinline__ float wsum(float v) {
    #pragma unroll
    for (int m = 32; m > 0; m >>= 1) v += __shfl_xor(v, m, 64);
    return v;
}
__device__ __forceinline__ float wmax(float v) {
    #pragma unroll
    for (int m = 32; m > 0; m >>= 1) v = fmaxf(v, __shfl_xor(v, m, 64));
    return v;
}

// grid = (5 groups, B). Block = 256 threads = 4 waves.
// wave w computes a1 columns [16w,16w+16); lane <-> triple t.
__launch_bounds__(256, 4)
__global__ void group_kernel(GPtrs gp, const int* __restrict__ items,
                             const float* __restrict__ E, const float* __restrict__ R,
                             const float* __restrict__ W1, const float* __restrict__ W2,
                             float* __restrict__ ws)
{
    const int g    = blockIdx.x;   // 0..4 : kgi, ddp, kgp, ddp1, ddo1
    const int b    = blockIdx.y;   // 0..B-1
    const int tid  = threadIdx.x;
    const int lane = tid & 63;
    const int wv   = __builtin_amdgcn_readfirstlane(tid >> 6); // wave id, SGPR

    __shared__ float xh[T][65];   // h rows (E[h0], later += E[h1])
    __shared__ float xp[T][65];   // p rows (R[r0], later *= R[r1])
    __shared__ float red[4][64];
    __shared__ int   sidx[6][T];  // h0,h1,r0,r1,t0,t1

    // ---- load indices ----
    const int* iptr0 = gp.h0[g]; const int* iptr1 = gp.h1[g];
    const int* iptr2 = gp.r0[g]; const int* iptr3 = gp.r1[g];
    const int* iptr4 = gp.t0[g]; const int* iptr5 = gp.t1[g];
    if (wv == 0) sidx[0][lane] = iptr0[b*T + lane];
    if (wv == 1) sidx[1][lane] = iptr1[b*T + lane];
    if (wv == 2) sidx[2][lane] = iptr2[b*T + lane];
    if (wv == 3) sidx[3][lane] = iptr3[b*T + lane];
    if (wv == 0) sidx[4][lane] = iptr4[b*T + lane];
    if (wv == 1) sidx[5][lane] = iptr5[b*T + lane];
    __syncthreads();

    // ---- stage xh = E[h0 rows], xp = R[r0 rows]; per-wave init partial ----
    float ip = 0.f;
    #pragma unroll 4
    for (int t = wv*16; t < wv*16+16; ++t) {
        float hv = E[sidx[0][t]*D + lane];
        float pv = R[sidx[2][t]*D + lane];
        xh[t][lane] = hv;
        xp[t][lane] = pv;
        ip += hv;
    }
    red[wv][lane] = ip;
    __syncthreads();

    // ---- init embedding ----
    if (wv == 0) {
        float iv;
        if (g == 1) iv = E[items[b]*D + lane];                       // ddp: E[items]
        else iv = (red[0][lane]+red[1][lane]+red[2][lane]+red[3][lane]) * (1.0f/64.0f);
        ws[((g*3 + 0)*BATCH + b)*D + lane] = iv;
    }
    __syncthreads();

    for (int L = 0; L < 2; ++L) {
        if (L == 1) {
            // h += E[h1], p *= R[r1]
            #pragma unroll 4
            for (int t = wv*16; t < wv*16+16; ++t) {
                xh[t][lane] += E[sidx[1][t]*D + lane];
                xp[t][lane] *= R[sidx[3][t]*D + lane];
            }
            __syncthreads();
        }

        // ---- X @ W1 (this wave: 16 output columns, lane = triple) ----
        float acc[16];
        #pragma unroll
        for (int jj = 0; jj < 16; ++jj) acc[jj] = 0.f;
        const float* w1c = W1 + wv*16;          // wave-uniform column base
        for (int k = 0; k < 64; ++k) {
            float xv = xh[lane][k];
            const float* wr = w1c + k*D;        // scalar loads (uniform addr)
            #pragma unroll
            for (int jj = 0; jj < 16; ++jj) acc[jj] = fmaf(xv, wr[jj], acc[jj]);
        }
        for (int k = 0; k < 64; ++k) {
            float xv = xp[lane][k];
            const float* wr = w1c + (64 + k)*D;
            #pragma unroll
            for (int jj = 0; jj < 16; ++jj) acc[jj] = fmaf(xv, wr[jj], acc[jj]);
        }

        // ---- sigmoid -> @W2 partial ----
        float lp = 0.f;
        #pragma unroll
        for (int jj = 0; jj < 16; ++jj) lp += sigmoidf_(acc[jj]) * W2[wv*16 + jj];
        red[wv][lane] = lp;
        __syncthreads();

        // ---- logits + softmax over T (lane <-> t), redundantly per wave ----
        float logit = sigmoidf_(red[0][lane]+red[1][lane]+red[2][lane]+red[3][lane]);
        float mx  = wmax(logit);
        float ex  = __expf(logit - mx);
        float sm  = wsum(ex);
        float att = ex / sm;
        __syncthreads();   // red about to be rewritten

        // ---- weighted sum of t rows: out[d] = sum_t att_t * E[tidx[t]][d] ----
        const int* tIdx = sidx[4 + L];
        float oacc = 0.f;
        #pragma unroll 4
        for (int t = wv*16; t < wv*16+16; ++t) {
            float a = __shfl(att, t, 64);
            oacc = fmaf(a, E[tIdx[t]*D + lane], oacc);
        }
        red[wv][lane] = oacc;
        __syncthreads();
        if (wv == 0) {
            ws[((g*3 + 1 + L)*BATCH + b)*D + lane] =
                red[0][lane]+red[1][lane]+red[2][lane]+red[3][lane];
        }
        __syncthreads();
    }
}

// score[b] = sigmoid( sum_i (kg[i]+kgp[i])·ddi1[i] + 2·ddi[i]·ddo1[i] )
__launch_bounds__(256, 4)
__global__ void combine_kernel(const float* __restrict__ ws, float* __restrict__ out)
{
    const int tid  = threadIdx.x;
    const int lane = tid & 63;
    const int wv   = tid >> 6;
    const int b    = blockIdx.x*4 + wv;
    float acc = 0.f;
    #pragma unroll
    for (int i = 0; i < 3; ++i) {
        float kg   = ws[((0*3+i)*BATCH + b)*D + lane];
        float ddi  = ws[((1*3+i)*BATCH + b)*D + lane];
        float kgp  = ws[((2*3+i)*BATCH + b)*D + lane];
        float ddi1 = ws[((3*3+i)*BATCH + b)*D + lane];
        float ddo1 = ws[((4*3+i)*BATCH + b)*D + lane];
        acc += (kg + kgp)*ddi1 + 2.0f*ddi*ddo1;
    }
    float s = wsum(acc);
    if (lane == 0) out[b] = 1.0f/(1.0f + __expf(-s));
}

extern "C" void kernel_launch(void* const* d_in, const int* in_sizes, int n_in,
                              void* d_out, int out_size, void* d_ws, size_t ws_size,
                              hipStream_t stream)
{
    // input order: 0 items; then 8 prefixes x {h0,h1,r0,r1,t0,t1}:
    // kgi@1, ddp@7, kgp@13, ddo@19(dead), kgi1@25(dead), ddp1@31, kgp1@37(dead), ddo1@43;
    // 49 emb0(unused), 50 emb1(unused), 51 entity_emb, 52 relation_emb, 53 W1, 54 W2
    const int gbase[5] = {1, 7, 13, 31, 43};   // kgi, ddp, kgp, ddp1, ddo1
    GPtrs gp;
    for (int g = 0; g < 5; ++g) {
        gp.h0[g] = (const int*)d_in[gbase[g]+0];
        gp.h1[g] = (const int*)d_in[gbase[g]+1];
        gp.r0[g] = (const int*)d_in[gbase[g]+2];
        gp.r1[g] = (const int*)d_in[gbase[g]+3];
        gp.t0[g] = (const int*)d_in[gbase[g]+4];
        gp.t1[g] = (const int*)d_in[gbase[g]+5];
    }
    const int*   items = (const int*)d_in[0];
    const float* E     = (const float*)d_in[51];
    const float* R     = (const float*)d_in[52];
    const float* W1    = (const float*)d_in[53];
    const float* W2    = (const float*)d_in[54];
    float* ws = (float*)d_ws;   // 5 groups x 3 embs x [B, D] = 15.7 MB

    dim3 grid(5, BATCH);
    group_kernel<<<grid, 256, 0, stream>>>(gp, items, E, R, W1, W2, ws);
    combine_kernel<<<BATCH/4, 256, 0, stream>>>(ws, (float*)d_out);
}

// Round 2
// 238.349 us; speedup vs baseline: 2.5782x; 2.5782x over previous
//
#include <hip/hip_runtime.h>

#define BATCH 4096
#define T 64
#define D 64
#define BPB 8          // batches per block
#define ROWDW 68       // padded row stride in dwords (64 bf16-pair dwords + 4 pad = 272B)

typedef __attribute__((ext_vector_type(8))) short bf16x8;
typedef __attribute__((ext_vector_type(4))) float f32x4;

struct GPtrs {
    const int* h0[5]; const int* h1[5];
    const int* r0[5]; const int* r1[5];
    const int* t0[5]; const int* t1[5];
};

__device__ __forceinline__ float sigmoidf_(float x){ return 1.0f/(1.0f+__expf(-x)); }

__device__ __forceinline__ unsigned short f2bf(float f){
    unsigned u = __float_as_uint(f);
    u += 0x7FFFu + ((u>>16)&1u);          // round-to-nearest-even
    return (unsigned short)(u>>16);
}
__device__ __forceinline__ float bf2f(unsigned h){
    return __uint_as_float(h<<16);
}
__device__ __forceinline__ unsigned pk2(float lo, float hi){
    return (unsigned)f2bf(lo) | ((unsigned)f2bf(hi)<<16);
}

__device__ __forceinline__ float wsum(float v){
    #pragma unroll
    for (int m=32;m>0;m>>=1) v += __shfl_xor(v,m,64);
    return v;
}
__device__ __forceinline__ float wmax(float v){
    #pragma unroll
    for (int m=32;m>0;m>>=1) v = fmaxf(v,__shfl_xor(v,m,64));
    return v;
}

union U4 { uint4 u4; bf16x8 v; };

// grid = (BATCH/BPB, 5 groups), block = 256 = 4 waves.
// Per b: C^T[j][t] = (X @ W1)^T via mfma_f32_16x16x32_bf16.
// Wave wv owns t-block wv (16 triples); A = W1^T (shared, LDS), B = X rows (LDS, wave-private).
__launch_bounds__(256, 3)
__global__ void group_kernel(GPtrs gp, const int* __restrict__ items,
                             const float* __restrict__ E, const float* __restrict__ R,
                             const float* __restrict__ W1, const float* __restrict__ W2,
                             float* __restrict__ ws)
{
    const int g    = blockIdx.y;
    const int tid  = threadIdx.x;
    const int lane = tid & 63;
    const int wv   = __builtin_amdgcn_readfirstlane(tid >> 6);

    __shared__ unsigned xb[T*ROWDW];    // X rows, bf16 pairs, padded: 17408 B
    __shared__ unsigned w1t[D*ROWDW];   // W1^T rows, bf16 pairs, padded: 17408 B
    __shared__ int   sidx[6][T];
    __shared__ float red[4][65];        // attention logits
    __shared__ float red2[4][65];       // init / output partials

    // ---- stage W1^T as bf16 (once per block) ----
    {
        int j  = tid & 63;
        int kp = tid >> 6;               // 0..3
        #pragma unroll
        for (int it=0; it<16; ++it, kp+=4) {
            float a = W1[(2*kp  )*D + j];
            float b = W1[(2*kp+1)*D + j];
            w1t[j*ROWDW + kp] = pk2(a,b);
        }
    }
    // ---- W2 fragment: j = jt*16 + (lane>>4)*4 + r (matches C/D row layout) ----
    float w2f[16];
    {
        int rbase = (lane>>4)<<2;
        #pragma unroll
        for (int jt=0;jt<4;jt++)
            #pragma unroll
            for (int r=0;r<4;r++)
                w2f[jt*4+r] = W2[jt*16 + rbase + r];
    }

    const int* gh0 = gp.h0[g]; const int* gh1 = gp.h1[g];
    const int* gr0 = gp.r0[g]; const int* gr1 = gp.r1[g];
    const int* gt0 = gp.t0[g]; const int* gt1 = gp.t1[g];

    #pragma unroll 1
    for (int bi=0; bi<BPB; ++bi) {
        const int b = blockIdx.x*BPB + bi;

        // ---- indices ----
        if (wv==0) sidx[0][lane] = gh0[b*T+lane];
        if (wv==1) sidx[1][lane] = gh1[b*T+lane];
        if (wv==2) sidx[2][lane] = gr0[b*T+lane];
        if (wv==3) sidx[3][lane] = gr1[b*T+lane];
        if (wv==0) sidx[4][lane] = gt0[b*T+lane];
        if (wv==1) sidx[5][lane] = gt1[b*T+lane];
        __syncthreads();                                    // A

        // ---- stage X = [E[h0] | R[r0]] as bf16 (wave-private rows) ----
        {
            int t = wv*16 + (lane>>2);
            int q = lane & 3;
            const float4* eh = (const float4*)(E + sidx[0][t]*D + q*16);
            float4 h0=eh[0], h1=eh[1], h2=eh[2], h3=eh[3];
            uint4 u0 = { pk2(h0.x,h0.y), pk2(h0.z,h0.w), pk2(h1.x,h1.y), pk2(h1.z,h1.w) };
            uint4 u1 = { pk2(h2.x,h2.y), pk2(h2.z,h2.w), pk2(h3.x,h3.y), pk2(h3.z,h3.w) };
            *(uint4*)&xb[t*ROWDW + q*8]     = u0;
            *(uint4*)&xb[t*ROWDW + q*8 + 4] = u1;
            const float4* rp = (const float4*)(R + sidx[2][t]*D + q*16);
            float4 p0=rp[0], p1=rp[1], p2=rp[2], p3=rp[3];
            uint4 v0 = { pk2(p0.x,p0.y), pk2(p0.z,p0.w), pk2(p1.x,p1.y), pk2(p1.z,p1.w) };
            uint4 v1 = { pk2(p2.x,p2.y), pk2(p2.z,p2.w), pk2(p3.x,p3.y), pk2(p3.z,p3.w) };
            *(uint4*)&xb[t*ROWDW + 32 + q*8]     = v0;
            *(uint4*)&xb[t*ROWDW + 32 + q*8 + 4] = v1;
        }
        __syncthreads();                                    // B

        // ---- init embedding (mean over h rows; ddp uses E[items]) ----
        {
            float s = 0.f;
            int kd = lane>>1;
            #pragma unroll
            for (int i=0;i<16;i++){
                unsigned u = xb[(wv*16+i)*ROWDW + kd];
                s += bf2f((lane&1)? (u>>16) : (u&0xFFFFu));
            }
            red2[wv][lane] = s;
            __syncthreads();                                // C
            if (wv==0) {
                float iv;
                if (g==1) iv = E[items[b]*D + lane];
                else iv = (red2[0][lane]+red2[1][lane]+red2[2][lane]+red2[3][lane])*(1.0f/64.0f);
                ws[((g*3+0)*BATCH + b)*D + lane] = iv;
            }
        }

        #pragma unroll
        for (int L=0; L<2; ++L) {
            if (L==1) {
                // update own rows in LDS: h += E[h1], p *= R[r1] (bf16 round-trip)
                int t = wv*16 + (lane>>2);
                int q = lane & 3;
                const float4* eh = (const float4*)(E + sidx[1][t]*D + q*16);
                float4 a0=eh[0], a1=eh[1], a2=eh[2], a3=eh[3];
                unsigned* ph = &xb[t*ROWDW + q*8];
                uint4 x0 = *(uint4*)ph;
                uint4 x1 = *(uint4*)(ph+4);
                x0.x = pk2(bf2f(x0.x&0xFFFFu)+a0.x, bf2f(x0.x>>16)+a0.y);
                x0.y = pk2(bf2f(x0.y&0xFFFFu)+a0.z, bf2f(x0.y>>16)+a0.w);
                x0.z = pk2(bf2f(x0.z&0xFFFFu)+a1.x, bf2f(x0.z>>16)+a1.y);
                x0.w = pk2(bf2f(x0.w&0xFFFFu)+a1.z, bf2f(x0.w>>16)+a1.w);
                x1.x = pk2(bf2f(x1.x&0xFFFFu)+a2.x, bf2f(x1.x>>16)+a2.y);
                x1.y = pk2(bf2f(x1.y&0xFFFFu)+a2.z, bf2f(x1.y>>16)+a2.w);
                x1.z = pk2(bf2f(x1.z&0xFFFFu)+a3.x, bf2f(x1.z>>16)+a3.y);
                x1.w = pk2(bf2f(x1.w&0xFFFFu)+a3.z, bf2f(x1.w>>16)+a3.w);
                *(uint4*)ph = x0; *(uint4*)(ph+4) = x1;
                const float4* rp = (const float4*)(R + sidx[3][t]*D + q*16);
                float4 c0=rp[0], c1=rp[1], c2=rp[2], c3=rp[3];
                unsigned* pp = &xb[t*ROWDW + 32 + q*8];
                uint4 y0 = *(uint4*)pp;
                uint4 y1 = *(uint4*)(pp+4);
                y0.x = pk2(bf2f(y0.x&0xFFFFu)*c0.x, bf2f(y0.x>>16)*c0.y);
                y0.y = pk2(bf2f(y0.y&0xFFFFu)*c0.z, bf2f(y0.y>>16)*c0.w);
                y0.z = pk2(bf2f(y0.z&0xFFFFu)*c1.x, bf2f(y0.z>>16)*c1.y);
                y0.w = pk2(bf2f(y0.w&0xFFFFu)*c1.z, bf2f(y0.w>>16)*c1.w);
                y1.x = pk2(bf2f(y1.x&0xFFFFu)*c2.x, bf2f(y1.x>>16)*c2.y);
                y1.y = pk2(bf2f(y1.y&0xFFFFu)*c2.z, bf2f(y1.y>>16)*c2.w);
                y1.z = pk2(bf2f(y1.z&0xFFFFu)*c3.x, bf2f(y1.z>>16)*c3.y);
                y1.w = pk2(bf2f(y1.w&0xFFFFu)*c3.z, bf2f(y1.w>>16)*c3.w);
                *(uint4*)pp = y0; *(uint4*)(pp+4) = y1;
                __syncthreads();                            // U
            }

            // ---- MFMA: C^T[j][t], t-block = wv, K = 128 ----
            U4 bu[4];
            const int trow = wv*16 + (lane&15);
            const int koff = (lane>>4)*4;
            #pragma unroll
            for (int ks=0;ks<4;ks++)
                bu[ks].u4 = *(const uint4*)&xb[trow*ROWDW + ks*16 + koff];
            f32x4 acc[4];
            #pragma unroll
            for (int jt=0;jt<4;jt++){
                f32x4 a = {0.f,0.f,0.f,0.f};
                #pragma unroll
                for (int ks=0;ks<4;ks++){
                    U4 wu;
                    wu.u4 = *(const uint4*)&w1t[(jt*16+(lane&15))*ROWDW + ks*16 + koff];
                    a = __builtin_amdgcn_mfma_f32_16x16x32_bf16(wu.v, bu[ks].v, a, 0,0,0);
                }
                acc[jt] = a;
            }

            // ---- attention logits: part_t = sum_j sigmoid(C^T[j][t]) * W2[j] ----
            float part = 0.f;
            #pragma unroll
            for (int jt=0;jt<4;jt++)
                #pragma unroll
                for (int r=0;r<4;r++)
                    part += sigmoidf_(acc[jt][r]) * w2f[jt*4+r];
            part += __shfl_xor(part,16,64);
            part += __shfl_xor(part,32,64);
            float logit = sigmoidf_(part);
            if (lane<16) red[wv][lane] = logit;
            __syncthreads();                                // D
            float lg  = red[lane>>4][lane&15];              // logit of t = lane
            float mx  = wmax(lg);
            float ex  = __expf(lg-mx);
            float att = ex / wsum(ex);

            // ---- weighted sum of target rows ----
            const int* tIdx = sidx[4+L];
            float oacc = 0.f;
            #pragma unroll
            for (int i=0;i<16;i++){
                int tt = wv*16+i;
                float a = __shfl(att, tt, 64);
                oacc = fmaf(a, E[tIdx[tt]*D + lane], oacc);
            }
            red2[wv][lane] = oacc;
            __syncthreads();                                // E
            if (wv==0)
                ws[((g*3+1+L)*BATCH + b)*D + lane] =
                    red2[0][lane]+red2[1][lane]+red2[2][lane]+red2[3][lane];
        }
    }
}

// score[b] = sigmoid( sum_i (kg[i]+kgp[i])·ddi1[i] + 2·ddi[i]·ddo1[i] )
__launch_bounds__(256, 4)
__global__ void combine_kernel(const float* __restrict__ ws, float* __restrict__ out)
{
    const int tid  = threadIdx.x;
    const int lane = tid & 63;
    const int wv   = tid >> 6;
    const int b    = blockIdx.x*4 + wv;
    float acc = 0.f;
    #pragma unroll
    for (int i = 0; i < 3; ++i) {
        float kg   = ws[((0*3+i)*BATCH + b)*D + lane];
        float ddi  = ws[((1*3+i)*BATCH + b)*D + lane];
        float kgp  = ws[((2*3+i)*BATCH + b)*D + lane];
        float ddi1 = ws[((3*3+i)*BATCH + b)*D + lane];
        float ddo1 = ws[((4*3+i)*BATCH + b)*D + lane];
        acc += (kg + kgp)*ddi1 + 2.0f*ddi*ddo1;
    }
    float s = wsum(acc);
    if (lane == 0) out[b] = 1.0f/(1.0f + __expf(-s));
}

extern "C" void kernel_launch(void* const* d_in, const int* in_sizes, int n_in,
                              void* d_out, int out_size, void* d_ws, size_t ws_size,
                              hipStream_t stream)
{
    // input order: 0 items; then 8 prefixes x {h0,h1,r0,r1,t0,t1}:
    // kgi@1, ddp@7, kgp@13, ddo@19(dead), kgi1@25(dead), ddp1@31, kgp1@37(dead), ddo1@43;
    // 49 emb0(unused), 50 emb1(unused), 51 entity_emb, 52 relation_emb, 53 W1, 54 W2
    const int gbase[5] = {1, 7, 13, 31, 43};   // kgi, ddp, kgp, ddp1, ddo1
    GPtrs gp;
    for (int g = 0; g < 5; ++g) {
        gp.h0[g] = (const int*)d_in[gbase[g]+0];
        gp.h1[g] = (const int*)d_in[gbase[g]+1];
        gp.r0[g] = (const int*)d_in[gbase[g]+2];
        gp.r1[g] = (const int*)d_in[gbase[g]+3];
        gp.t0[g] = (const int*)d_in[gbase[g]+4];
        gp.t1[g] = (const int*)d_in[gbase[g]+5];
    }
    const int*   items = (const int*)d_in[0];
    const float* E     = (const float*)d_in[51];
    const float* R     = (const float*)d_in[52];
    const float* W1    = (const float*)d_in[53];
    const float* W2    = (const float*)d_in[54];
    float* ws = (float*)d_ws;   // 5 groups x 3 embs x [B, D] = 15.7 MB

    dim3 grid(BATCH/BPB, 5);
    group_kernel<<<grid, 256, 0, stream>>>(gp, items, E, R, W1, W2, ws);
    combine_kernel<<<BATCH/4, 256, 0, stream>>>(ws, (float*)d_out);
}